// Round 11
// baseline (203.603 us; speedup 1.0000x reference)
//
#include <hip/hip_runtime.h>
#include <hip/hip_fp16.h>

// MessagePassingLayer, pull-based CSR + MFMA node GEMMs (r10) + packed records
// + 2-node gather:
//  mfmaA: FUSED y=relu(x@Wm+bm), tq=x@Wu[0:64]+bu via mfma_f32_16x16x32_f16;
//  partA: 98 dst-buckets of 1024 nodes, CHUNK=2048; rec = w:32|dloc:10|src:17
//         packed in ONE u64 (dlocS side-array deleted -> less scattered traffic);
//  partB: 1024 thr/bucket, inline bucket-prefix, count pass reads low-4B only;
//  gather: half-wave per TWO nodes, joint 4+4 MLP loop (8 recs + 8 y-rows in
//          flight across both lists) + 8/4/1 drains -> 2x memory-level parallelism;
//  updB2: MFMA h=relu(tq + agg@Wu[64:128]) + 16-lane shfl L2-norm, in-place.

#define DIM 64
#define NPB 1024
#define LOG_NPB 10
#define NBUCK_MAX 128
#define CAP 16384
#define CHUNK 2048
#define EPT 8
#define SRCM 0x1FFFFu

typedef _Float16 half8 __attribute__((ext_vector_type(8)));
typedef float f32x4 __attribute__((ext_vector_type(4)));

// ---------------- fused node GEMMs: y = relu(x@Wm+bm), tq = x@Wu_top+bu ----------------
__global__ __launch_bounds__(256) void k_mfmaA(
    const float* __restrict__ x, const float* __restrict__ Wm,
    const float* __restrict__ bm, const float* __restrict__ Wu,
    const float* __restrict__ bu, __half* __restrict__ y,
    __half* __restrict__ tq, int n) {
  int l = threadIdx.x & 63;
  int wv = threadIdx.x >> 6;
  int r = l & 15, g = l >> 4;

  half8 Bm[2][4], Bu[2][4];
#pragma unroll
  for (int ks = 0; ks < 2; ++ks)
#pragma unroll
    for (int ct = 0; ct < 4; ++ct) {
      int c = ct * 16 + r;
#pragma unroll
      for (int j = 0; j < 8; ++j) {
        int k = ks * 32 + g * 8 + j;
        Bm[ks][ct][j] = (_Float16)Wm[k * 64 + c];
        Bu[ks][ct][j] = (_Float16)Wu[k * 64 + c];
      }
    }
  float bmv[4], buv[4];
#pragma unroll
  for (int ct = 0; ct < 4; ++ct) { bmv[ct] = bm[ct * 16 + r]; buv[ct] = bu[ct * 16 + r]; }

  int ntiles = (n + 15) >> 4;
  int tile = blockIdx.x * 4 + wv;
  if (tile >= ntiles) return;
  int row0 = tile << 4;

  int arow = row0 + r; if (arow >= n) arow = n - 1;
  const float* xr = x + (size_t)arow * 64;
  half8 A[2];
#pragma unroll
  for (int ks = 0; ks < 2; ++ks) {
    float4 v0 = *(const float4*)(xr + ks * 32 + g * 8);
    float4 v1 = *(const float4*)(xr + ks * 32 + g * 8 + 4);
    A[ks][0] = (_Float16)v0.x; A[ks][1] = (_Float16)v0.y;
    A[ks][2] = (_Float16)v0.z; A[ks][3] = (_Float16)v0.w;
    A[ks][4] = (_Float16)v1.x; A[ks][5] = (_Float16)v1.y;
    A[ks][6] = (_Float16)v1.z; A[ks][7] = (_Float16)v1.w;
  }

  f32x4 Dm[4], Du[4];
#pragma unroll
  for (int ct = 0; ct < 4; ++ct)
#pragma unroll
    for (int q = 0; q < 4; ++q) { Dm[ct][q] = bmv[ct]; Du[ct][q] = buv[ct]; }

#pragma unroll
  for (int ks = 0; ks < 2; ++ks)
#pragma unroll
    for (int ct = 0; ct < 4; ++ct) {
      Dm[ct] = __builtin_amdgcn_mfma_f32_16x16x32_f16(A[ks], Bm[ks][ct], Dm[ct], 0, 0, 0);
      Du[ct] = __builtin_amdgcn_mfma_f32_16x16x32_f16(A[ks], Bu[ks][ct], Du[ct], 0, 0, 0);
    }

  // C/D: col = ct*16 + (lane&15), row = (lane>>4)*4 + q   [m89-verified]
#pragma unroll
  for (int q = 0; q < 4; ++q) {
    int row = row0 + g * 4 + q;
    if (row < n) {
#pragma unroll
      for (int ct = 0; ct < 4; ++ct) {
        y[(size_t)row * 64 + ct * 16 + r]  = __float2half(fmaxf(Dm[ct][q], 0.0f));
        tq[(size_t)row * 64 + ct * 16 + r] = __float2half(Du[ct][q]);
      }
    }
  }
}

// ---------------- partA: bucket-partition edges, packed records ----------------
__global__ __launch_bounds__(256) void k_partA(
    const int* __restrict__ src, const int* __restrict__ dst,
    const float* __restrict__ ew, unsigned long long* __restrict__ recS,
    int* __restrict__ bucketCur, int E, int nbuck) {
  __shared__ int hist[NBUCK_MAX];
  __shared__ int gbase[NBUCK_MAX];
  int t = threadIdx.x;
  int base = blockIdx.x * CHUNK;

  for (int b = t; b < nbuck; b += 256) hist[b] = 0;
  __syncthreads();

  unsigned long long rec[EPT];
  short bk[EPT];
#pragma unroll
  for (int i = 0; i < EPT; ++i) {
    int e = base + i * 256 + t;
    if (e < E) {
      int d = dst[e];
      int b = d >> LOG_NPB;
      bk[i] = (short)b;
      rec[i] = ((unsigned long long)__float_as_uint(ew[e]) << 32)
             | ((unsigned long long)(d & (NPB - 1)) << 17)
             | (unsigned)src[e];
      atomicAdd(&hist[b], 1);
    } else {
      bk[i] = -1;
    }
  }
  __syncthreads();
  for (int b = t; b < nbuck; b += 256)
    gbase[b] = atomicAdd(&bucketCur[b], hist[b]);
  __syncthreads();
  for (int b = t; b < nbuck; b += 256) hist[b] = 0;
  __syncthreads();
#pragma unroll
  for (int i = 0; i < EPT; ++i) {
    if (bk[i] >= 0) {
      int b = bk[i];
      int lp = gbase[b] + atomicAdd(&hist[b], 1);
      if (lp < CAP) recS[(size_t)b * CAP + lp] = rec[i];
    }
  }
}

// ---------------- partB: per-bucket count + scan + bin ----------------
__global__ __launch_bounds__(1024) void k_partB(
    const unsigned long long* __restrict__ recS, const int* __restrict__ bucketCur,
    unsigned long long* __restrict__ sw, int* __restrict__ cnt,
    int* __restrict__ rowstart, int n) {
  __shared__ int lcnt[NPB];
  __shared__ int loff[NPB];
  __shared__ int wsum[16];
  int b = blockIdx.x;
  int t = threadIdx.x;
  int m = bucketCur[b];
  if (m > CAP) m = CAP;
  size_t sbase = (size_t)b * CAP;
  int bktbase = 0;
  for (int q = 0; q < b; ++q) bktbase += bucketCur[q];   // uniform scalar loop

  const unsigned* recLo = (const unsigned*)recS;         // low 4B: dloc|src

  lcnt[t] = 0;
  __syncthreads();
  for (int i = t; i < m; i += 1024)
    atomicAdd(&lcnt[(recLo[2 * (sbase + i)] >> 17) & (NPB - 1)], 1);
  __syncthreads();

  int v = lcnt[t];
  int lane = t & 63;
  int incl = v;
#pragma unroll
  for (int off = 1; off < 64; off <<= 1) {
    int tt = __shfl_up(incl, off, 64);
    if (lane >= off) incl += tt;
  }
  if (lane == 63) wsum[t >> 6] = incl;
  __syncthreads();
  int woff = 0;
  for (int q = 0; q < (t >> 6); ++q) woff += wsum[q];
  int excl = incl - v + woff;
  loff[t] = excl;
  int gn = (b << LOG_NPB) + t;
  if (gn < n) {
    cnt[gn] = v;
    rowstart[gn] = bktbase + excl;
  }
  __syncthreads();

  for (int i = t; i < m; i += 1024) {
    unsigned long long rec = recS[sbase + i];
    int dl = (int)((rec >> 17) & (NPB - 1));
    int p = atomicAdd(&loff[dl], 1);
    sw[bktbase + p] = rec;
  }
}

// ---------------- pull-gather: half-wave per TWO nodes, joint 4+4 MLP ----------------
#define YLOAD(rr) y2[(size_t)(unsigned)((rr) & SRCM) * 32 + lane]
#define WOF(rr) __uint_as_float((unsigned)((rr) >> 32))

__global__ __launch_bounds__(256) void k_gather(
    const unsigned long long* __restrict__ sw, const int* __restrict__ rowstart,
    const int* __restrict__ cnt, const __half2* __restrict__ y2,
    float* __restrict__ agg, int n) {
  int lane = threadIdx.x & 31;
  int h = (int)((blockIdx.x * (size_t)blockDim.x + threadIdx.x) >> 5);
  int n0 = h * 2, n1 = h * 2 + 1;
  if (n0 >= n) return;

  int c0 = cnt[n0], e0 = rowstart[n0], E0 = e0 + c0;
  float a0x = 0.0f, a0y = 0.0f, a1x = 0.0f, a1y = 0.0f;
  int c1 = 0, e1 = 0, E1 = 0;
  if (n1 < n) { c1 = cnt[n1]; e1 = rowstart[n1]; E1 = e1 + c1; }

  // joint loop: 4 edges from each node -> 8 recs + 8 y-rows in flight
  while (e0 + 4 <= E0 && e1 + 4 <= E1) {
    unsigned long long r0 = sw[e0 + 0];
    unsigned long long r1 = sw[e0 + 1];
    unsigned long long r2 = sw[e0 + 2];
    unsigned long long r3 = sw[e0 + 3];
    unsigned long long r4 = sw[e1 + 0];
    unsigned long long r5 = sw[e1 + 1];
    unsigned long long r6 = sw[e1 + 2];
    unsigned long long r7 = sw[e1 + 3];
    __half2 v0 = YLOAD(r0); __half2 v1 = YLOAD(r1);
    __half2 v2 = YLOAD(r2); __half2 v3 = YLOAD(r3);
    __half2 v4 = YLOAD(r4); __half2 v5 = YLOAD(r5);
    __half2 v6 = YLOAD(r6); __half2 v7 = YLOAD(r7);
    float w0 = WOF(r0), w1 = WOF(r1), w2 = WOF(r2), w3 = WOF(r3);
    float w4 = WOF(r4), w5 = WOF(r5), w6 = WOF(r6), w7 = WOF(r7);
    float2 f0 = __half22float2(v0); float2 f1 = __half22float2(v1);
    float2 f2 = __half22float2(v2); float2 f3 = __half22float2(v3);
    float2 f4 = __half22float2(v4); float2 f5 = __half22float2(v5);
    float2 f6 = __half22float2(v6); float2 f7 = __half22float2(v7);
    a0x = fmaf(f0.x, w0, a0x); a0y = fmaf(f0.y, w0, a0y);
    a0x = fmaf(f1.x, w1, a0x); a0y = fmaf(f1.y, w1, a0y);
    a0x = fmaf(f2.x, w2, a0x); a0y = fmaf(f2.y, w2, a0y);
    a0x = fmaf(f3.x, w3, a0x); a0y = fmaf(f3.y, w3, a0y);
    a1x = fmaf(f4.x, w4, a1x); a1y = fmaf(f4.y, w4, a1y);
    a1x = fmaf(f5.x, w5, a1x); a1y = fmaf(f5.y, w5, a1y);
    a1x = fmaf(f6.x, w6, a1x); a1y = fmaf(f6.y, w6, a1y);
    a1x = fmaf(f7.x, w7, a1x); a1y = fmaf(f7.y, w7, a1y);
    e0 += 4; e1 += 4;
  }

  // drain node0 then node1: 8 / 4 / 1
#pragma unroll
  for (int s = 0; s < 2; ++s) {
    int e = s ? e1 : e0;
    int E_ = s ? E1 : E0;
    float ax = 0.0f, ay = 0.0f;
    for (; e + 8 <= E_; e += 8) {
      unsigned long long r0 = sw[e + 0], r1 = sw[e + 1], r2 = sw[e + 2], r3 = sw[e + 3];
      unsigned long long r4 = sw[e + 4], r5 = sw[e + 5], r6 = sw[e + 6], r7 = sw[e + 7];
      __half2 v0 = YLOAD(r0); __half2 v1 = YLOAD(r1);
      __half2 v2 = YLOAD(r2); __half2 v3 = YLOAD(r3);
      __half2 v4 = YLOAD(r4); __half2 v5 = YLOAD(r5);
      __half2 v6 = YLOAD(r6); __half2 v7 = YLOAD(r7);
      float w0 = WOF(r0), w1 = WOF(r1), w2 = WOF(r2), w3 = WOF(r3);
      float w4 = WOF(r4), w5 = WOF(r5), w6 = WOF(r6), w7 = WOF(r7);
      float2 f0 = __half22float2(v0); float2 f1 = __half22float2(v1);
      float2 f2 = __half22float2(v2); float2 f3 = __half22float2(v3);
      float2 f4 = __half22float2(v4); float2 f5 = __half22float2(v5);
      float2 f6 = __half22float2(v6); float2 f7 = __half22float2(v7);
      ax = fmaf(f0.x, w0, ax); ay = fmaf(f0.y, w0, ay);
      ax = fmaf(f1.x, w1, ax); ay = fmaf(f1.y, w1, ay);
      ax = fmaf(f2.x, w2, ax); ay = fmaf(f2.y, w2, ay);
      ax = fmaf(f3.x, w3, ax); ay = fmaf(f3.y, w3, ay);
      ax = fmaf(f4.x, w4, ax); ay = fmaf(f4.y, w4, ay);
      ax = fmaf(f5.x, w5, ax); ay = fmaf(f5.y, w5, ay);
      ax = fmaf(f6.x, w6, ax); ay = fmaf(f6.y, w6, ay);
      ax = fmaf(f7.x, w7, ax); ay = fmaf(f7.y, w7, ay);
    }
    for (; e + 4 <= E_; e += 4) {
      unsigned long long r0 = sw[e + 0], r1 = sw[e + 1], r2 = sw[e + 2], r3 = sw[e + 3];
      __half2 v0 = YLOAD(r0); __half2 v1 = YLOAD(r1);
      __half2 v2 = YLOAD(r2); __half2 v3 = YLOAD(r3);
      float w0 = WOF(r0), w1 = WOF(r1), w2 = WOF(r2), w3 = WOF(r3);
      float2 f0 = __half22float2(v0); float2 f1 = __half22float2(v1);
      float2 f2 = __half22float2(v2); float2 f3 = __half22float2(v3);
      ax = fmaf(f0.x, w0, ax); ay = fmaf(f0.y, w0, ay);
      ax = fmaf(f1.x, w1, ax); ay = fmaf(f1.y, w1, ay);
      ax = fmaf(f2.x, w2, ax); ay = fmaf(f2.y, w2, ay);
      ax = fmaf(f3.x, w3, ax); ay = fmaf(f3.y, w3, ay);
    }
    for (; e < E_; ++e) {
      unsigned long long r = sw[e];
      __half2 vv = YLOAD(r);
      float w = WOF(r);
      float2 f = __half22float2(vv);
      ax = fmaf(f.x, w, ax); ay = fmaf(f.y, w, ay);
    }
    if (s) { a1x += ax; a1y += ay; } else { a0x += ax; a0y += ay; }
  }

  float invd0 = 1.0f / fmaxf((float)c0, 1.0f);
  float2 o0; o0.x = a0x * invd0; o0.y = a0y * invd0;
  *(float2*)&agg[(size_t)n0 * 64 + lane * 2] = o0;
  if (n1 < n) {
    float invd1 = 1.0f / fmaxf((float)c1, 1.0f);
    float2 o1; o1.x = a1x * invd1; o1.y = a1y * invd1;
    *(float2*)&agg[(size_t)n1 * 64 + lane * 2] = o1;
  }
}

// ---------------- MFMA updB: out = l2norm(relu(tq + agg@Wu[64:128])) in-place ----------------
__global__ __launch_bounds__(256) void k_updB2(
    const float* __restrict__ agg /* == out (d_out) */,
    const __half* __restrict__ tq, const float* __restrict__ Wu,
    float* __restrict__ out, int n) {
  int l = threadIdx.x & 63;
  int wv = threadIdx.x >> 6;
  int r = l & 15, g = l >> 4;

  half8 B2[2][4];
#pragma unroll
  for (int ks = 0; ks < 2; ++ks)
#pragma unroll
    for (int ct = 0; ct < 4; ++ct) {
      int c = ct * 16 + r;
#pragma unroll
      for (int j = 0; j < 8; ++j) {
        int k = 64 + ks * 32 + g * 8 + j;     // agg-part rows of Wu
        B2[ks][ct][j] = (_Float16)Wu[k * 64 + c];
      }
    }

  int ntiles = (n + 15) >> 4;
  int tile = blockIdx.x * 4 + wv;
  if (tile >= ntiles) return;
  int row0 = tile << 4;

  int arow = row0 + r; if (arow >= n) arow = n - 1;
  const float* ar = agg + (size_t)arow * 64;
  half8 A[2];
#pragma unroll
  for (int ks = 0; ks < 2; ++ks) {
    float4 v0 = *(const float4*)(ar + ks * 32 + g * 8);
    float4 v1 = *(const float4*)(ar + ks * 32 + g * 8 + 4);
    A[ks][0] = (_Float16)v0.x; A[ks][1] = (_Float16)v0.y;
    A[ks][2] = (_Float16)v0.z; A[ks][3] = (_Float16)v0.w;
    A[ks][4] = (_Float16)v1.x; A[ks][5] = (_Float16)v1.y;
    A[ks][6] = (_Float16)v1.z; A[ks][7] = (_Float16)v1.w;
  }

  f32x4 D[4];
#pragma unroll
  for (int ct = 0; ct < 4; ++ct)
#pragma unroll
    for (int q = 0; q < 4; ++q) {
      int row = row0 + g * 4 + q;
      D[ct][q] = (row < n) ? __half2float(tq[(size_t)row * 64 + ct * 16 + r]) : 0.0f;
    }

#pragma unroll
  for (int ks = 0; ks < 2; ++ks)
#pragma unroll
    for (int ct = 0; ct < 4; ++ct)
      D[ct] = __builtin_amdgcn_mfma_f32_16x16x32_f16(A[ks], B2[ks][ct], D[ct], 0, 0, 0);

#pragma unroll
  for (int q = 0; q < 4; ++q) {
    float h0 = fmaxf(D[0][q], 0.0f);
    float h1 = fmaxf(D[1][q], 0.0f);
    float h2 = fmaxf(D[2][q], 0.0f);
    float h3 = fmaxf(D[3][q], 0.0f);
    float ss = h0 * h0 + h1 * h1 + h2 * h2 + h3 * h3;
#pragma unroll
    for (int off = 1; off < 16; off <<= 1) ss += __shfl_xor(ss, off, 64);
    float inv = 1.0f / fmaxf(sqrtf(ss), 1e-12f);
    int row = row0 + g * 4 + q;
    if (row < n) {
      out[(size_t)row * 64 + 0 * 16 + r] = h0 * inv;
      out[(size_t)row * 64 + 1 * 16 + r] = h1 * inv;
      out[(size_t)row * 64 + 2 * 16 + r] = h2 * inv;
      out[(size_t)row * 64 + 3 * 16 + r] = h3 * inv;
    }
  }
}

extern "C" void kernel_launch(void* const* d_in, const int* in_sizes, int n_in,
                              void* d_out, int out_size, void* d_ws, size_t ws_size,
                              hipStream_t stream) {
  const float* x  = (const float*)d_in[0];
  const int*   ei = (const int*)d_in[1];
  const float* ew = (const float*)d_in[2];
  const float* Wm = (const float*)d_in[3];
  const float* bm = (const float*)d_in[4];
  const float* Wu = (const float*)d_in[5];
  const float* bu = (const float*)d_in[6];

  int n = in_sizes[0] / DIM;   // 100000
  int E = in_sizes[2];         // 1200000
  const int* srcIdx = ei;
  const int* dstIdx = ei + E;
  int nbuck = (n + NPB - 1) >> LOG_NPB;   // 98

  // workspace (~36.1 MB): y | sw | recS (tq aliases after partB) | cnt | rowstart
  __half* y = (__half*)d_ws;                                            // n*64 fp16
  unsigned long long* sw = (unsigned long long*)(y + (size_t)n * DIM);  // E u64
  unsigned long long* recS = sw + E;                                    // nbuck*CAP u64
  int* cnt      = (int*)(recS + (size_t)nbuck * CAP);                   // n
  int* rowstart = cnt + n;                                              // n
  int* bucketCur = rowstart + n;                                        // NBUCK_MAX
  __half* tq = (__half*)recS;   // alias: recS dead after k_partB (12.85MB >= 12.8)

  hipMemsetAsync(bucketCur, 0, NBUCK_MAX * sizeof(int), stream);

  int nblkA = (E + CHUNK - 1) / CHUNK;    // 586
  k_partA<<<nblkA, 256, 0, stream>>>(srcIdx, dstIdx, ew, recS, bucketCur, E, nbuck);
  k_partB<<<nbuck, 1024, 0, stream>>>(recS, bucketCur, sw, cnt, rowstart, n);

  int ntiles = (n + 15) >> 4;
  int nblkG = (ntiles + 3) / 4;           // 1563
  k_mfmaA<<<nblkG, 256, 0, stream>>>(x, Wm, bm, Wu, bu, y, tq, n);  // tq overwrites recS
  int nhw = (n + 1) / 2;                  // half-waves (2 nodes each)
  k_gather<<<(nhw + 7) / 8, 256, 0, stream>>>(sw, rowstart, cnt, (const __half2*)y,
                                              (float*)d_out, n);
  k_updB2<<<nblkG, 256, 0, stream>>>((const float*)d_out, tq, Wu, (float*)d_out, n);
}